// Round 11
// baseline (3392.970 us; speedup 1.0000x reference)
//
#include <hip/hip_runtime.h>

// GCN forward, MI355X. v11 — panels + XCD work-queues kept from v10 (FETCH
// 38MB proved L2-residency works); k_agg inner loop rebuilt: 16-lane group
// per node, full-64B-line gathers, register accumulation, NO cross-lane
// reduction, per-wave queue items (v10's 344us was bpermute-latency-bound).

#define N_NODES 50000
#define N_EDGES 800000
#define D 128
#define NSH 8
#define PANEL ((size_t)N_NODES * 16)

__device__ __forceinline__ int get_xcd() {
    unsigned id;
    asm("s_getreg_b32 %0, hwreg(HW_REG_XCC_ID)" : "=s"(id));
    return (int)(id & (NSH - 1));
}

// ---------------- CSR build ----------------

__global__ __launch_bounds__(256) void k_count(const int* __restrict__ src, const int* __restrict__ dst,
                                               int* __restrict__ deg8, int* __restrict__ row8, int ne) {
    int e = blockIdx.x * 256 + threadIdx.x;
    int sh = get_xcd() * N_NODES;
    if (e < ne) {
        atomicAdd(&deg8[sh + src[e]], 1);
        atomicAdd(&row8[sh + dst[e]], 1);
    }
}

__global__ __launch_bounds__(256) void k_merge(const int* __restrict__ deg8, const int* __restrict__ row8,
                                               float* __restrict__ dinv, int* __restrict__ rowm, int n) {
    int i = blockIdx.x * 256 + threadIdx.x;
    if (i < n) {
        int ds = 0, rs = 0;
#pragma unroll
        for (int k = 0; k < NSH; k++) { ds += deg8[k * N_NODES + i]; rs += row8[k * N_NODES + i]; }
        dinv[i] = 1.0f / (float)(ds > 1 ? ds : 1);
        rowm[i] = rs;
    }
}

__global__ __launch_bounds__(1024) void k_scan1(const int* __restrict__ cnt, int* __restrict__ excl,
                                                int* __restrict__ blocksum, int n) {
    __shared__ int wsum[16];
    int i = blockIdx.x * 1024 + threadIdx.x;
    int v = (i < n) ? cnt[i] : 0;
    int lane = threadIdx.x & 63, wid = threadIdx.x >> 6;
    int x = v;
#pragma unroll
    for (int off = 1; off < 64; off <<= 1) {
        int y = __shfl_up(x, off, 64);
        if (lane >= off) x += y;
    }
    if (lane == 63) wsum[wid] = x;
    __syncthreads();
    if (threadIdx.x == 0) {
        int run = 0;
        for (int w = 0; w < 16; w++) { int t = wsum[w]; wsum[w] = run; run += t; }
        blocksum[blockIdx.x] = run;
    }
    __syncthreads();
    if (i < n) excl[i] = (x - v) + wsum[wid];
}

__global__ void k_scan2(const int* __restrict__ blocksum, int* __restrict__ blockoff,
                        int* __restrict__ rowptr_last, int nblk) {
    if (threadIdx.x == 0) {
        int run = 0;
        for (int b = 0; b < nblk; b++) { int t = blocksum[b]; blockoff[b] = run; run += t; }
        rowptr_last[0] = run;
    }
}

__global__ __launch_bounds__(1024) void k_scan3(int* __restrict__ excl, const int* __restrict__ blockoff, int n) {
    int i = blockIdx.x * 1024 + threadIdx.x;
    if (i < n) excl[i] += blockoff[blockIdx.x];
}

__global__ __launch_bounds__(256) void k_fill(const int* __restrict__ src, const int* __restrict__ dst,
                                              const int* __restrict__ rowptr, int* __restrict__ fillcnt,
                                              int* __restrict__ csrc, int ne) {
    int e = blockIdx.x * 256 + threadIdx.x;
    if (e < ne) {
        int d = dst[e];
        int pos = atomicAdd(&fillcnt[d], 1);
        csrc[rowptr[d] + pos] = src[e];
    }
}

// ---------------- panelize: outp[p][node][16] = features[node][p*16..] * dinv[node] ----------------

__global__ __launch_bounds__(256) void k_panelize(const float* __restrict__ in, const float* __restrict__ dinv,
                                                  float* __restrict__ outp) {
    int tid = blockIdx.x * 256 + threadIdx.x;          // N_NODES*32 threads
    if (tid >= N_NODES * 32) return;
    int p = tid / (N_NODES * 4);
    int r = tid - p * (N_NODES * 4);
    int node = r >> 2, qq = r & 3;
    float w = dinv[node];
    float4 v = *reinterpret_cast<const float4*>(&in[(size_t)node * D + p * 16 + qq * 4]);
    v.x *= w; v.y *= w; v.z *= w; v.w *= w;
    *reinterpret_cast<float4*>(&outp[(size_t)p * PANEL + (size_t)node * 16 + qq * 4]) = v;
}

// ---------------- SpMM aggregation: per-XCD slice queues, 16-lane node groups ----------------
// 16-lane group owns one node+slice: per edge, lanes load one contiguous 64B
// line pan[src*16 + l16] and accumulate in a register. No shuffles/barriers.
// Queue item = 16 nodes, fetched per-wave (lane0 atomic + shfl broadcast);
// slice order starts at this block's physical XCD -> L2-resident panel.

__global__ __launch_bounds__(256) void k_agg(const float* __restrict__ hp,
                                             const int* __restrict__ rp, const int* __restrict__ csrc,
                                             float* __restrict__ outp, int* __restrict__ q) {
    const int t = threadIdx.x;
    const int L = t & 63;
    const int grp = (t >> 4) & 3;         // 4 groups per wave
    const int l16 = t & 15;
    const int myx = get_xcd();
    const int NI = N_NODES / 16;          // 3125 items x 16 nodes
    for (int so = 0; so < NSH; so++) {
        int slice = (myx + so) & (NSH - 1);
        const float* __restrict__ pan = hp + (size_t)slice * PANEL;
        float* __restrict__ opan = outp + (size_t)slice * PANEL;
        for (;;) {
            int item = 0;
            if (L == 0) item = atomicAdd(&q[slice], 1);
            item = __shfl(item, 0, 64);
            if (item >= NI) break;
            int node0 = item * 16 + grp * 4;
#pragma unroll
            for (int u = 0; u < 4; u++) {
                int node = node0 + u;
                int s0 = rp[node], s1 = rp[node + 1];
                float acc = 0.f;
                int e = s0;
                for (; e + 4 <= s1; e += 4) {
                    int i0 = csrc[e],     i1 = csrc[e + 1];
                    int i2 = csrc[e + 2], i3 = csrc[e + 3];
                    float a = pan[(size_t)i0 * 16 + l16];
                    float b = pan[(size_t)i1 * 16 + l16];
                    float c = pan[(size_t)i2 * 16 + l16];
                    float d = pan[(size_t)i3 * 16 + l16];
                    acc += (a + b) + (c + d);
                }
                for (; e < s1; e++) acc += pan[(size_t)csrc[e] * 16 + l16];
                opan[(size_t)node * 16 + l16] = acc;
            }
        }
    }
}

// ---------------- dense layer, panel I/O (+ fused epilogues) ----------------

__global__ __launch_bounds__(256) void k_gemm(const float* __restrict__ in, const float* __restrict__ W,
                                              const float* __restrict__ bias, float* __restrict__ out,
                                              int nrows, int relu,
                                              const float* __restrict__ dscale,
                                              const float* __restrict__ pw, const float* __restrict__ pb,
                                              float* __restrict__ pi_out, float* __restrict__ colsum) {
    __shared__ float wl[D * D];      // 64 KB
    __shared__ float at[D * 32];     // 16 KB (80 KB total: 2 blocks/CU)
    int t = threadIdx.x;
    const int head = (pw != nullptr);
    for (int i = t; i < D * D / 4; i += 256)
        reinterpret_cast<float4*>(wl)[i] = reinterpret_cast<const float4*>(W)[i];
    const int tx = t & 31;
    const int ty = t >> 5;
    const int ldrow = t & 31;
    const int ldc   = t >> 5;        // = panel index for staging
    float4 bv = reinterpret_cast<const float4*>(bias)[tx];
    float4 pwv = head ? reinterpret_cast<const float4*>(pw)[tx] : float4{0.f, 0.f, 0.f, 0.f};
    float pb0 = head ? pb[0] : 0.f;
    const int op = tx >> 2, oq = tx & 3;   // output panel / offset
    float cs0 = 0.f, cs1 = 0.f, cs2 = 0.f, cs3 = 0.f;
    int ntiles = (nrows + 31) / 32;

    for (int tile = blockIdx.x; tile < ntiles; tile += gridDim.x) {
        int row0 = tile * 32;
        __syncthreads();
        {
            int gr = row0 + ldrow;
            float va[16];
            if (gr < nrows) {
                const float4* ap = reinterpret_cast<const float4*>(&in[(size_t)ldc * PANEL + (size_t)gr * 16]);
#pragma unroll
                for (int qq = 0; qq < 4; qq++) {
                    float4 v = ap[qq];
                    va[qq * 4 + 0] = v.x; va[qq * 4 + 1] = v.y;
                    va[qq * 4 + 2] = v.z; va[qq * 4 + 3] = v.w;
                }
            } else {
#pragma unroll
                for (int qq = 0; qq < 16; qq++) va[qq] = 0.f;
            }
            int kb = ldc * 16;
#pragma unroll
            for (int j = 0; j < 16; j++) at[(kb + j) * 32 + ldrow] = va[j];
        }
        __syncthreads();

        float acc[4][4];
#pragma unroll
        for (int j = 0; j < 4; j++)
#pragma unroll
            for (int c = 0; c < 4; c++) acc[j][c] = 0.f;

#pragma unroll 8
        for (int k = 0; k < D; k++) {
            float4 a = *reinterpret_cast<const float4*>(&at[k * 32 + ty * 4]);
            float4 w = *reinterpret_cast<const float4*>(&wl[k * D + tx * 4]);
            acc[0][0] += a.x * w.x; acc[0][1] += a.x * w.y; acc[0][2] += a.x * w.z; acc[0][3] += a.x * w.w;
            acc[1][0] += a.y * w.x; acc[1][1] += a.y * w.y; acc[1][2] += a.y * w.z; acc[1][3] += a.y * w.w;
            acc[2][0] += a.z * w.x; acc[2][1] += a.z * w.y; acc[2][2] += a.z * w.z; acc[2][3] += a.z * w.w;
            acc[3][0] += a.w * w.x; acc[3][1] += a.w * w.y; acc[3][2] += a.w * w.z; acc[3][3] += a.w * w.w;
        }

#pragma unroll
        for (int j = 0; j < 4; j++) {
            int gr = row0 + ty * 4 + j;
            if (gr < nrows) {
                float4 o;
                o.x = acc[j][0] + bv.x; o.y = acc[j][1] + bv.y;
                o.z = acc[j][2] + bv.z; o.w = acc[j][3] + bv.w;
                if (relu) {
                    o.x = fmaxf(o.x, 0.f); o.y = fmaxf(o.y, 0.f);
                    o.z = fmaxf(o.z, 0.f); o.w = fmaxf(o.w, 0.f);
                }
                if (head) {
                    cs0 += o.x; cs1 += o.y; cs2 += o.z; cs3 += o.w;
                    float pr = o.x * pwv.x + o.y * pwv.y + o.z * pwv.z + o.w * pwv.w;
#pragma unroll
                    for (int off = 16; off > 0; off >>= 1) pr += __shfl_xor(pr, off, 32);
                    if (tx == 0) pi_out[gr] = pr + pb0;
                } else {
                    if (dscale) {
                        float w = dscale[gr];
                        o.x *= w; o.y *= w; o.z *= w; o.w *= w;
                    }
                    *reinterpret_cast<float4*>(&out[(size_t)op * PANEL + (size_t)gr * 16 + oq * 4]) = o;
                }
            }
        }
    }

    if (head) {
        __syncthreads();
        float* csl = at;
        if (t < D) csl[t] = 0.f;
        __syncthreads();
        atomicAdd(&csl[tx * 4 + 0], cs0);
        atomicAdd(&csl[tx * 4 + 1], cs1);
        atomicAdd(&csl[tx * 4 + 2], cs2);
        atomicAdd(&csl[tx * 4 + 3], cs3);
        __syncthreads();
        if (t < D) atomicAdd(&colsum[t], csl[t]);
    }
}

// ---------------- value head ----------------

__global__ __launch_bounds__(128) void k_value(const float* __restrict__ colsum, const float* __restrict__ vw,
                                               const float* __restrict__ vb, float* __restrict__ out) {
    __shared__ float red[128];
    int t = threadIdx.x;
    red[t] = (colsum[t] * (1.0f / (float)N_NODES)) * vw[t];
    __syncthreads();
    for (int s = 64; s > 0; s >>= 1) {
        if (t < s) red[t] += red[t + s];
        __syncthreads();
    }
    if (t == 0) out[0] = red[0] + vb[0];
}

__global__ __launch_bounds__(64) void k_ws_too_small(float* __restrict__ out, int n) {
    int i = blockIdx.x * 64 + threadIdx.x;
    if (i < n) out[i] = -1e30f;
}

// ---------------- launch ----------------

extern "C" void kernel_launch(void* const* d_in, const int* in_sizes, int n_in,
                              void* d_out, int out_size, void* d_ws, size_t ws_size,
                              hipStream_t stream) {
    const float* features = (const float*)d_in[0];
    const int*   src      = (const int*)d_in[1];
    const int*   dst      = (const int*)d_in[2];
    const float* W1 = (const float*)d_in[3];
    const float* b1 = (const float*)d_in[4];
    const float* W2 = (const float*)d_in[5];
    const float* b2 = (const float*)d_in[6];
    const float* W3 = (const float*)d_in[7];
    const float* b3 = (const float*)d_in[8];
    const float* pw = (const float*)d_in[9];
    const float* pb = (const float*)d_in[10];
    const float* vw = (const float*)d_in[11];
    const float* vb = (const float*)d_in[12];
    float* out = (float*)d_out;

    char* ws = (char*)d_ws;
    size_t off = 0;
    auto alloc = [&](size_t bytes) -> char* {
        char* p = ws + off;
        off += (bytes + 255) & ~(size_t)255;
        return p;
    };
    float* dinv     = (float*)alloc((size_t)N_NODES * 4);
    int*   rowptr   = (int*)alloc((size_t)(N_NODES + 1) * 4);
    int*   blocksum = (int*)alloc(64 * 4);
    int*   blockoff = (int*)alloc(64 * 4);
    float* colsum   = (float*)alloc(D * 4);
    int*   qs       = (int*)alloc(3 * NSH * 4);
    int*   csrc     = (int*)alloc((size_t)N_EDGES * 4);
    float* bufA     = (float*)alloc((size_t)N_NODES * D * 4);
    float* bufB     = (float*)alloc((size_t)N_NODES * D * 4);

    // CSR-build temporaries overlay bufB (dead until agg-1 output lands in bufB).
    int* deg8    = (int*)bufB;
    int* row8    = deg8 + (size_t)NSH * N_NODES;
    int* rowm    = row8 + (size_t)NSH * N_NODES;
    int* fillcnt = rowm + N_NODES;

    if (off > ws_size) {
        k_ws_too_small<<<(out_size + 63) / 64, 64, 0, stream>>>(out, out_size);
        return;
    }

    hipMemsetAsync(deg8,    0, (size_t)NSH * N_NODES * 4, stream);
    hipMemsetAsync(row8,    0, (size_t)NSH * N_NODES * 4, stream);
    hipMemsetAsync(fillcnt, 0, (size_t)N_NODES * 4, stream);
    hipMemsetAsync(colsum,  0, (size_t)D * 4, stream);
    hipMemsetAsync(qs,      0, 3 * NSH * 4, stream);

    int eblocks = (N_EDGES + 255) / 256;
    k_count<<<eblocks, 256, 0, stream>>>(src, dst, deg8, row8, N_EDGES);
    k_merge<<<(N_NODES + 255) / 256, 256, 0, stream>>>(deg8, row8, dinv, rowm, N_NODES);

    int nblk = (N_NODES + 1023) / 1024;
    k_scan1<<<nblk, 1024, 0, stream>>>(rowm, rowptr, blocksum, N_NODES);
    k_scan2<<<1, 64, 0, stream>>>(blocksum, blockoff, rowptr + N_NODES, nblk);
    k_scan3<<<nblk, 1024, 0, stream>>>(rowptr, blockoff, N_NODES);
    k_fill<<<eblocks, 256, 0, stream>>>(src, dst, rowptr, fillcnt, csrc, N_EDGES);

    // panelize features*dinv -> bufA (panels)
    k_panelize<<<(N_NODES * 32 + 255) / 256, 256, 0, stream>>>(features, dinv, bufA);

    // layer 1: agg(bufA)->bufB ; gemm in-place panels (+dinv scale for next layer)
    k_agg<<<2048, 256, 0, stream>>>(bufA, rowptr, csrc, bufB, qs);
    k_gemm<<<512, 256, 0, stream>>>(bufB, W1, b1, bufB, N_NODES, 1, dinv,
                                    nullptr, nullptr, nullptr, nullptr);
    // layer 2
    k_agg<<<2048, 256, 0, stream>>>(bufB, rowptr, csrc, bufA, qs + NSH);
    k_gemm<<<512, 256, 0, stream>>>(bufA, W2, b2, bufA, N_NODES, 1, dinv,
                                    nullptr, nullptr, nullptr, nullptr);
    // layer 3: head mode (PI -> out, colsum; h3 never stored)
    k_agg<<<2048, 256, 0, stream>>>(bufA, rowptr, csrc, bufB, qs + 2 * NSH);
    k_gemm<<<512, 256, 0, stream>>>(bufB, W3, b3, nullptr, N_NODES, 0, nullptr,
                                    pw, pb, out, colsum);

    k_value<<<1, 128, 0, stream>>>(colsum, vw, vb, out + N_NODES);
}

// Round 12
// 437.807 us; speedup vs baseline: 7.7499x; 7.7499x over previous
//
#include <hip/hip_runtime.h>

// GCN forward, MI355X. v12 — proven pieces only: panels [8][N][16] (v10:
// FETCH 175->38MB) + static slice=bid&7 (T1 round-robin) + v8-style parallel
// compute: 1 node per 16-lane group, 1 (chunk,slice) per block, 4-deep
// pipelined 64B line-gathers, no shuffles/atomics/barriers in agg.
// v11 lesson: never serialize multiple nodes per wave behind dynamic loops.

#define N_NODES 50000
#define N_EDGES 800000
#define D 128
#define NSH 8
#define PANEL ((size_t)N_NODES * 16)

__device__ __forceinline__ int get_xcd() {
    unsigned id;
    asm("s_getreg_b32 %0, hwreg(HW_REG_XCC_ID)" : "=s"(id));
    return (int)(id & (NSH - 1));
}

// ---------------- CSR build ----------------

__global__ __launch_bounds__(256) void k_count(const int* __restrict__ src, const int* __restrict__ dst,
                                               int* __restrict__ deg8, int* __restrict__ row8, int ne) {
    int e = blockIdx.x * 256 + threadIdx.x;
    int sh = get_xcd() * N_NODES;
    if (e < ne) {
        atomicAdd(&deg8[sh + src[e]], 1);
        atomicAdd(&row8[sh + dst[e]], 1);
    }
}

__global__ __launch_bounds__(256) void k_merge(const int* __restrict__ deg8, const int* __restrict__ row8,
                                               float* __restrict__ dinv, int* __restrict__ rowm, int n) {
    int i = blockIdx.x * 256 + threadIdx.x;
    if (i < n) {
        int ds = 0, rs = 0;
#pragma unroll
        for (int k = 0; k < NSH; k++) { ds += deg8[k * N_NODES + i]; rs += row8[k * N_NODES + i]; }
        dinv[i] = 1.0f / (float)(ds > 1 ? ds : 1);
        rowm[i] = rs;
    }
}

__global__ __launch_bounds__(1024) void k_scan1(const int* __restrict__ cnt, int* __restrict__ excl,
                                                int* __restrict__ blocksum, int n) {
    __shared__ int wsum[16];
    int i = blockIdx.x * 1024 + threadIdx.x;
    int v = (i < n) ? cnt[i] : 0;
    int lane = threadIdx.x & 63, wid = threadIdx.x >> 6;
    int x = v;
#pragma unroll
    for (int off = 1; off < 64; off <<= 1) {
        int y = __shfl_up(x, off, 64);
        if (lane >= off) x += y;
    }
    if (lane == 63) wsum[wid] = x;
    __syncthreads();
    if (threadIdx.x == 0) {
        int run = 0;
        for (int w = 0; w < 16; w++) { int t = wsum[w]; wsum[w] = run; run += t; }
        blocksum[blockIdx.x] = run;
    }
    __syncthreads();
    if (i < n) excl[i] = (x - v) + wsum[wid];
}

__global__ void k_scan2(const int* __restrict__ blocksum, int* __restrict__ blockoff,
                        int* __restrict__ rowptr_last, int nblk) {
    if (threadIdx.x == 0) {
        int run = 0;
        for (int b = 0; b < nblk; b++) { int t = blocksum[b]; blockoff[b] = run; run += t; }
        rowptr_last[0] = run;
    }
}

__global__ __launch_bounds__(1024) void k_scan3(int* __restrict__ excl, const int* __restrict__ blockoff, int n) {
    int i = blockIdx.x * 1024 + threadIdx.x;
    if (i < n) excl[i] += blockoff[blockIdx.x];
}

__global__ __launch_bounds__(256) void k_fill(const int* __restrict__ src, const int* __restrict__ dst,
                                              const int* __restrict__ rowptr, int* __restrict__ fillcnt,
                                              int* __restrict__ csrc, int ne) {
    int e = blockIdx.x * 256 + threadIdx.x;
    if (e < ne) {
        int d = dst[e];
        int pos = atomicAdd(&fillcnt[d], 1);
        csrc[rowptr[d] + pos] = src[e];
    }
}

// ---------------- panelize: outp[p][node][16] = features[node][p*16..] * dinv[node] ----------------

__global__ __launch_bounds__(256) void k_panelize(const float* __restrict__ in, const float* __restrict__ dinv,
                                                  float* __restrict__ outp) {
    int tid = blockIdx.x * 256 + threadIdx.x;          // N_NODES*32 threads
    if (tid >= N_NODES * 32) return;
    int p = tid / (N_NODES * 4);
    int r = tid - p * (N_NODES * 4);
    int node = r >> 2, qq = r & 3;
    float w = dinv[node];
    float4 v = *reinterpret_cast<const float4*>(&in[(size_t)node * D + p * 16 + qq * 4]);
    v.x *= w; v.y *= w; v.z *= w; v.w *= w;
    *reinterpret_cast<float4*>(&outp[(size_t)p * PANEL + (size_t)node * 16 + qq * 4]) = v;
}

// ---------------- SpMM aggregation: panels, static XCD slices, max TLP ----------------
// Block (25000 total) = (chunk = bid>>3, slice = bid&7). 16 groups x 16 lanes;
// group g owns node chunk*16+g. Per 4-edge step: 4 independent 64B line-loads
// per group, register accumulate. No shuffles, no barriers, no atomics.

__global__ __launch_bounds__(256) void k_agg(const float* __restrict__ hp,
                                             const int* __restrict__ rp, const int* __restrict__ csrc,
                                             float* __restrict__ outp) {
    const int l16 = threadIdx.x & 15;
    const int grp = threadIdx.x >> 4;               // 0..15
    const int slice = blockIdx.x & (NSH - 1);
    const int node = (blockIdx.x >> 3) * 16 + grp;  // 3125*16 == N_NODES
    const float* __restrict__ pan = hp + (size_t)slice * PANEL;
    int s0 = rp[node], s1 = rp[node + 1];
    float acc = 0.f;
    int e = s0;
    for (; e + 4 <= s1; e += 4) {
        int i0 = csrc[e],     i1 = csrc[e + 1];
        int i2 = csrc[e + 2], i3 = csrc[e + 3];
        float a = pan[(size_t)i0 * 16 + l16];
        float b = pan[(size_t)i1 * 16 + l16];
        float c = pan[(size_t)i2 * 16 + l16];
        float d = pan[(size_t)i3 * 16 + l16];
        acc += (a + b) + (c + d);
    }
    for (; e < s1; e++) acc += pan[(size_t)csrc[e] * 16 + l16];
    outp[(size_t)slice * PANEL + (size_t)node * 16 + l16] = acc;
}

// ---------------- dense layer, panel I/O (+ fused epilogues) ----------------

__global__ __launch_bounds__(256) void k_gemm(const float* __restrict__ in, const float* __restrict__ W,
                                              const float* __restrict__ bias, float* __restrict__ out,
                                              int nrows, int relu,
                                              const float* __restrict__ dscale,
                                              const float* __restrict__ pw, const float* __restrict__ pb,
                                              float* __restrict__ pi_out, float* __restrict__ colsum) {
    __shared__ float wl[D * D];      // 64 KB
    __shared__ float at[D * 32];     // 16 KB (80 KB total: 2 blocks/CU)
    int t = threadIdx.x;
    const int head = (pw != nullptr);
    for (int i = t; i < D * D / 4; i += 256)
        reinterpret_cast<float4*>(wl)[i] = reinterpret_cast<const float4*>(W)[i];
    const int tx = t & 31;
    const int ty = t >> 5;
    const int ldrow = t & 31;
    const int ldc   = t >> 5;        // = panel index for staging
    float4 bv = reinterpret_cast<const float4*>(bias)[tx];
    float4 pwv = head ? reinterpret_cast<const float4*>(pw)[tx] : float4{0.f, 0.f, 0.f, 0.f};
    float pb0 = head ? pb[0] : 0.f;
    const int op = tx >> 2, oq = tx & 3;   // output panel / offset
    float cs0 = 0.f, cs1 = 0.f, cs2 = 0.f, cs3 = 0.f;
    int ntiles = (nrows + 31) / 32;

    for (int tile = blockIdx.x; tile < ntiles; tile += gridDim.x) {
        int row0 = tile * 32;
        __syncthreads();
        {
            int gr = row0 + ldrow;
            float va[16];
            if (gr < nrows) {
                const float4* ap = reinterpret_cast<const float4*>(&in[(size_t)ldc * PANEL + (size_t)gr * 16]);
#pragma unroll
                for (int qq = 0; qq < 4; qq++) {
                    float4 v = ap[qq];
                    va[qq * 4 + 0] = v.x; va[qq * 4 + 1] = v.y;
                    va[qq * 4 + 2] = v.z; va[qq * 4 + 3] = v.w;
                }
            } else {
#pragma unroll
                for (int qq = 0; qq < 16; qq++) va[qq] = 0.f;
            }
            int kb = ldc * 16;
#pragma unroll
            for (int j = 0; j < 16; j++) at[(kb + j) * 32 + ldrow] = va[j];
        }
        __syncthreads();

        float acc[4][4];
#pragma unroll
        for (int j = 0; j < 4; j++)
#pragma unroll
            for (int c = 0; c < 4; c++) acc[j][c] = 0.f;

#pragma unroll 8
        for (int k = 0; k < D; k++) {
            float4 a = *reinterpret_cast<const float4*>(&at[k * 32 + ty * 4]);
            float4 w = *reinterpret_cast<const float4*>(&wl[k * D + tx * 4]);
            acc[0][0] += a.x * w.x; acc[0][1] += a.x * w.y; acc[0][2] += a.x * w.z; acc[0][3] += a.x * w.w;
            acc[1][0] += a.y * w.x; acc[1][1] += a.y * w.y; acc[1][2] += a.y * w.z; acc[1][3] += a.y * w.w;
            acc[2][0] += a.z * w.x; acc[2][1] += a.z * w.y; acc[2][2] += a.z * w.z; acc[2][3] += a.z * w.w;
            acc[3][0] += a.w * w.x; acc[3][1] += a.w * w.y; acc[3][2] += a.w * w.z; acc[3][3] += a.w * w.w;
        }

#pragma unroll
        for (int j = 0; j < 4; j++) {
            int gr = row0 + ty * 4 + j;
            if (gr < nrows) {
                float4 o;
                o.x = acc[j][0] + bv.x; o.y = acc[j][1] + bv.y;
                o.z = acc[j][2] + bv.z; o.w = acc[j][3] + bv.w;
                if (relu) {
                    o.x = fmaxf(o.x, 0.f); o.y = fmaxf(o.y, 0.f);
                    o.z = fmaxf(o.z, 0.f); o.w = fmaxf(o.w, 0.f);
                }
                if (head) {
                    cs0 += o.x; cs1 += o.y; cs2 += o.z; cs3 += o.w;
                    float pr = o.x * pwv.x + o.y * pwv.y + o.z * pwv.z + o.w * pwv.w;
#pragma unroll
                    for (int off = 16; off > 0; off >>= 1) pr += __shfl_xor(pr, off, 32);
                    if (tx == 0) pi_out[gr] = pr + pb0;
                } else {
                    if (dscale) {
                        float w = dscale[gr];
                        o.x *= w; o.y *= w; o.z *= w; o.w *= w;
                    }
                    *reinterpret_cast<float4*>(&out[(size_t)op * PANEL + (size_t)gr * 16 + oq * 4]) = o;
                }
            }
        }
    }

    if (head) {
        __syncthreads();
        float* csl = at;
        if (t < D) csl[t] = 0.f;
        __syncthreads();
        atomicAdd(&csl[tx * 4 + 0], cs0);
        atomicAdd(&csl[tx * 4 + 1], cs1);
        atomicAdd(&csl[tx * 4 + 2], cs2);
        atomicAdd(&csl[tx * 4 + 3], cs3);
        __syncthreads();
        if (t < D) atomicAdd(&colsum[t], csl[t]);
    }
}

// ---------------- value head ----------------

__global__ __launch_bounds__(128) void k_value(const float* __restrict__ colsum, const float* __restrict__ vw,
                                               const float* __restrict__ vb, float* __restrict__ out) {
    __shared__ float red[128];
    int t = threadIdx.x;
    red[t] = (colsum[t] * (1.0f / (float)N_NODES)) * vw[t];
    __syncthreads();
    for (int s = 64; s > 0; s >>= 1) {
        if (t < s) red[t] += red[t + s];
        __syncthreads();
    }
    if (t == 0) out[0] = red[0] + vb[0];
}

__global__ __launch_bounds__(64) void k_ws_too_small(float* __restrict__ out, int n) {
    int i = blockIdx.x * 64 + threadIdx.x;
    if (i < n) out[i] = -1e30f;
}

// ---------------- launch ----------------

extern "C" void kernel_launch(void* const* d_in, const int* in_sizes, int n_in,
                              void* d_out, int out_size, void* d_ws, size_t ws_size,
                              hipStream_t stream) {
    const float* features = (const float*)d_in[0];
    const int*   src      = (const int*)d_in[1];
    const int*   dst      = (const int*)d_in[2];
    const float* W1 = (const float*)d_in[3];
    const float* b1 = (const float*)d_in[4];
    const float* W2 = (const float*)d_in[5];
    const float* b2 = (const float*)d_in[6];
    const float* W3 = (const float*)d_in[7];
    const float* b3 = (const float*)d_in[8];
    const float* pw = (const float*)d_in[9];
    const float* pb = (const float*)d_in[10];
    const float* vw = (const float*)d_in[11];
    const float* vb = (const float*)d_in[12];
    float* out = (float*)d_out;

    char* ws = (char*)d_ws;
    size_t off = 0;
    auto alloc = [&](size_t bytes) -> char* {
        char* p = ws + off;
        off += (bytes + 255) & ~(size_t)255;
        return p;
    };
    float* dinv     = (float*)alloc((size_t)N_NODES * 4);
    int*   rowptr   = (int*)alloc((size_t)(N_NODES + 1) * 4);
    int*   blocksum = (int*)alloc(64 * 4);
    int*   blockoff = (int*)alloc(64 * 4);
    float* colsum   = (float*)alloc(D * 4);
    int*   csrc     = (int*)alloc((size_t)N_EDGES * 4);
    float* bufA     = (float*)alloc((size_t)N_NODES * D * 4);
    float* bufB     = (float*)alloc((size_t)N_NODES * D * 4);

    // CSR-build temporaries overlay bufB (dead once agg-1 writes bufB).
    int* deg8    = (int*)bufB;
    int* row8    = deg8 + (size_t)NSH * N_NODES;
    int* rowm    = row8 + (size_t)NSH * N_NODES;
    int* fillcnt = rowm + N_NODES;

    if (off > ws_size) {
        k_ws_too_small<<<(out_size + 63) / 64, 64, 0, stream>>>(out, out_size);
        return;
    }

    hipMemsetAsync(deg8,    0, (size_t)NSH * N_NODES * 4, stream);
    hipMemsetAsync(row8,    0, (size_t)NSH * N_NODES * 4, stream);
    hipMemsetAsync(fillcnt, 0, (size_t)N_NODES * 4, stream);
    hipMemsetAsync(colsum,  0, (size_t)D * 4, stream);

    int eblocks = (N_EDGES + 255) / 256;
    k_count<<<eblocks, 256, 0, stream>>>(src, dst, deg8, row8, N_EDGES);
    k_merge<<<(N_NODES + 255) / 256, 256, 0, stream>>>(deg8, row8, dinv, rowm, N_NODES);

    int nblk = (N_NODES + 1023) / 1024;
    k_scan1<<<nblk, 1024, 0, stream>>>(rowm, rowptr, blocksum, N_NODES);
    k_scan2<<<1, 64, 0, stream>>>(blocksum, blockoff, rowptr + N_NODES, nblk);
    k_scan3<<<nblk, 1024, 0, stream>>>(rowptr, blockoff, N_NODES);
    k_fill<<<eblocks, 256, 0, stream>>>(src, dst, rowptr, fillcnt, csrc, N_EDGES);

    // panelize features*dinv -> bufA (panels)
    k_panelize<<<(N_NODES * 32 + 255) / 256, 256, 0, stream>>>(features, dinv, bufA);

    int aggblocks = (N_NODES / 16) * NSH;    // 25000
    // layer 1: agg(bufA)->bufB ; gemm in-place panels (+dinv scale for next layer)
    k_agg<<<aggblocks, 256, 0, stream>>>(bufA, rowptr, csrc, bufB);
    k_gemm<<<512, 256, 0, stream>>>(bufB, W1, b1, bufB, N_NODES, 1, dinv,
                                    nullptr, nullptr, nullptr, nullptr);
    // layer 2
    k_agg<<<aggblocks, 256, 0, stream>>>(bufB, rowptr, csrc, bufA);
    k_gemm<<<512, 256, 0, stream>>>(bufA, W2, b2, bufA, N_NODES, 1, dinv,
                                    nullptr, nullptr, nullptr, nullptr);
    // layer 3: head mode (PI -> out, colsum; h3 never stored)
    k_agg<<<aggblocks, 256, 0, stream>>>(bufA, rowptr, csrc, bufB);
    k_gemm<<<512, 256, 0, stream>>>(bufB, W3, b3, nullptr, N_NODES, 0, nullptr,
                                    pw, pb, out, colsum);

    k_value<<<1, 128, 0, stream>>>(colsum, vw, vb, out + N_NODES);
}

// Round 13
// 380.403 us; speedup vs baseline: 8.9194x; 1.1509x over previous
//
#include <hip/hip_runtime.h>

// GCN forward, MI355X. v13 — (1) k_agg: 4-lane float4 column-owner groups
// (panels + static slice=bid&7 kept; 2.5x fewer inst/edge, 4x bytes/load,
// still no cross-lane reduce), int4 edge-index loads. (2) k_fill atomics
// removed: k_count's row atomic returns the position (pos[e]); shadows
// dropped (v8 proved no benefit). k_count stays at its 62us fabric floor.

#define N_NODES 50000
#define N_EDGES 800000
#define D 128
#define NSH 8
#define PANEL ((size_t)N_NODES * 16)

// ---------------- CSR build ----------------

__global__ __launch_bounds__(256) void k_count(const int* __restrict__ src, const int* __restrict__ dst,
                                               int* __restrict__ degcnt, int* __restrict__ rowcnt,
                                               int* __restrict__ pos, int ne) {
    int e = blockIdx.x * 256 + threadIdx.x;
    if (e < ne) {
        atomicAdd(&degcnt[src[e]], 1);                 // out-degree (norm='left')
        pos[e] = atomicAdd(&rowcnt[dst[e]], 1);        // in-degree + within-row position
    }
}

__global__ __launch_bounds__(256) void k_deginv(const int* __restrict__ degcnt, float* __restrict__ dinv, int n) {
    int i = blockIdx.x * 256 + threadIdx.x;
    if (i < n) {
        int d = degcnt[i];
        dinv[i] = 1.0f / (float)(d > 1 ? d : 1);
    }
}

__global__ __launch_bounds__(1024) void k_scan1(const int* __restrict__ cnt, int* __restrict__ excl,
                                                int* __restrict__ blocksum, int n) {
    __shared__ int wsum[16];
    int i = blockIdx.x * 1024 + threadIdx.x;
    int v = (i < n) ? cnt[i] : 0;
    int lane = threadIdx.x & 63, wid = threadIdx.x >> 6;
    int x = v;
#pragma unroll
    for (int off = 1; off < 64; off <<= 1) {
        int y = __shfl_up(x, off, 64);
        if (lane >= off) x += y;
    }
    if (lane == 63) wsum[wid] = x;
    __syncthreads();
    if (threadIdx.x == 0) {
        int run = 0;
        for (int w = 0; w < 16; w++) { int t = wsum[w]; wsum[w] = run; run += t; }
        blocksum[blockIdx.x] = run;
    }
    __syncthreads();
    if (i < n) excl[i] = (x - v) + wsum[wid];
}

__global__ void k_scan2(const int* __restrict__ blocksum, int* __restrict__ blockoff,
                        int* __restrict__ rowptr_last, int nblk) {
    if (threadIdx.x == 0) {
        int run = 0;
        for (int b = 0; b < nblk; b++) { int t = blocksum[b]; blockoff[b] = run; run += t; }
        rowptr_last[0] = run;
    }
}

__global__ __launch_bounds__(1024) void k_scan3(int* __restrict__ excl, const int* __restrict__ blockoff, int n) {
    int i = blockIdx.x * 1024 + threadIdx.x;
    if (i < n) excl[i] += blockoff[blockIdx.x];
}

__global__ __launch_bounds__(256) void k_fill(const int* __restrict__ src, const int* __restrict__ dst,
                                              const int* __restrict__ rowptr, const int* __restrict__ pos,
                                              int* __restrict__ csrc, int ne) {
    int e = blockIdx.x * 256 + threadIdx.x;
    if (e < ne) {
        csrc[rowptr[dst[e]] + pos[e]] = src[e];        // pure scatter, no atomics
    }
}

// ---------------- panelize: outp[p][node][16] = features[node][p*16..] * dinv[node] ----------------

__global__ __launch_bounds__(256) void k_panelize(const float* __restrict__ in, const float* __restrict__ dinv,
                                                  float* __restrict__ outp) {
    int tid = blockIdx.x * 256 + threadIdx.x;          // N_NODES*32 threads
    if (tid >= N_NODES * 32) return;
    int p = tid / (N_NODES * 4);
    int r = tid - p * (N_NODES * 4);
    int node = r >> 2, qq = r & 3;
    float w = dinv[node];
    float4 v = *reinterpret_cast<const float4*>(&in[(size_t)node * D + p * 16 + qq * 4]);
    v.x *= w; v.y *= w; v.z *= w; v.w *= w;
    *reinterpret_cast<float4*>(&outp[(size_t)p * PANEL + (size_t)node * 16 + qq * 4]) = v;
}

// ---------------- SpMM aggregation: panels, static XCD slices, float4 lanes ----------------
// Block = 64 groups x 4 lanes; group owns one node, lane owns 4 cols of the
// 16-col slice. Per edge: one dwordx4 per lane (group covers the 64B line),
// register float4 accumulate — no shuffles/atomics/barriers. Edge indices
// read as int4 (aligned). slice = bid&7 -> L2-resident 3.2MB panel per XCD.

__global__ __launch_bounds__(256) void k_agg(const float* __restrict__ hp,
                                             const int* __restrict__ rp, const int* __restrict__ csrc,
                                             float* __restrict__ outp) {
    const int l4 = threadIdx.x & 3;
    const int grp = threadIdx.x >> 2;               // 0..63
    const int slice = blockIdx.x & (NSH - 1);
    const int node = (blockIdx.x >> 3) * 64 + grp;
    if (node >= N_NODES) return;
    const float* __restrict__ pan = hp + (size_t)slice * PANEL + l4 * 4;
    int s0 = rp[node], s1 = rp[node + 1];
    float4 acc = {0.f, 0.f, 0.f, 0.f};
    int e = s0;
    int npre = (s0 + 3) & ~3; if (npre > s1) npre = s1;
    for (; e < npre; e++) {                          // align to int4
        float4 a = *reinterpret_cast<const float4*>(&pan[(size_t)csrc[e] * 16]);
        acc.x += a.x; acc.y += a.y; acc.z += a.z; acc.w += a.w;
    }
    for (; e + 4 <= s1; e += 4) {
        int4 ii = *reinterpret_cast<const int4*>(&csrc[e]);
        float4 a = *reinterpret_cast<const float4*>(&pan[(size_t)ii.x * 16]);
        float4 b = *reinterpret_cast<const float4*>(&pan[(size_t)ii.y * 16]);
        float4 c = *reinterpret_cast<const float4*>(&pan[(size_t)ii.z * 16]);
        float4 d = *reinterpret_cast<const float4*>(&pan[(size_t)ii.w * 16]);
        acc.x += (a.x + b.x) + (c.x + d.x);
        acc.y += (a.y + b.y) + (c.y + d.y);
        acc.z += (a.z + b.z) + (c.z + d.z);
        acc.w += (a.w + b.w) + (c.w + d.w);
    }
    for (; e < s1; e++) {
        float4 a = *reinterpret_cast<const float4*>(&pan[(size_t)csrc[e] * 16]);
        acc.x += a.x; acc.y += a.y; acc.z += a.z; acc.w += a.w;
    }
    *reinterpret_cast<float4*>(&outp[(size_t)slice * PANEL + (size_t)node * 16 + l4 * 4]) = acc;
}

// ---------------- dense layer, panel I/O (+ fused epilogues) ----------------

__global__ __launch_bounds__(256) void k_gemm(const float* __restrict__ in, const float* __restrict__ W,
                                              const float* __restrict__ bias, float* __restrict__ out,
                                              int nrows, int relu,
                                              const float* __restrict__ dscale,
                                              const float* __restrict__ pw, const float* __restrict__ pb,
                                              float* __restrict__ pi_out, float* __restrict__ colsum) {
    __shared__ float wl[D * D];      // 64 KB
    __shared__ float at[D * 32];     // 16 KB (80 KB total: 2 blocks/CU)
    int t = threadIdx.x;
    const int head = (pw != nullptr);
    for (int i = t; i < D * D / 4; i += 256)
        reinterpret_cast<float4*>(wl)[i] = reinterpret_cast<const float4*>(W)[i];
    const int tx = t & 31;
    const int ty = t >> 5;
    const int ldrow = t & 31;
    const int ldc   = t >> 5;        // = panel index for staging
    float4 bv = reinterpret_cast<const float4*>(bias)[tx];
    float4 pwv = head ? reinterpret_cast<const float4*>(pw)[tx] : float4{0.f, 0.f, 0.f, 0.f};
    float pb0 = head ? pb[0] : 0.f;
    const int op = tx >> 2, oq = tx & 3;   // output panel / offset
    float cs0 = 0.f, cs1 = 0.f, cs2 = 0.f, cs3 = 0.f;
    int ntiles = (nrows + 31) / 32;

    for (int tile = blockIdx.x; tile < ntiles; tile += gridDim.x) {
        int row0 = tile * 32;
        __syncthreads();
        {
            int gr = row0 + ldrow;
            float va[16];
            if (gr < nrows) {
                const float4* ap = reinterpret_cast<const float4*>(&in[(size_t)ldc * PANEL + (size_t)gr * 16]);
#pragma unroll
                for (int qq = 0; qq < 4; qq++) {
                    float4 v = ap[qq];
                    va[qq * 4 + 0] = v.x; va[qq * 4 + 1] = v.y;
                    va[qq * 4 + 2] = v.z; va[qq * 4 + 3] = v.w;
                }
            } else {
#pragma unroll
                for (int qq = 0; qq < 16; qq++) va[qq] = 0.f;
            }
            int kb = ldc * 16;
#pragma unroll
            for (int j = 0; j < 16; j++) at[(kb + j) * 32 + ldrow] = va[j];
        }
        __syncthreads();

        float acc[4][4];
#pragma unroll
        for (int j = 0; j < 4; j++)
#pragma unroll
            for (int c = 0; c < 4; c++) acc[j][c] = 0.f;

#pragma unroll 8
        for (int k = 0; k < D; k++) {
            float4 a = *reinterpret_cast<const float4*>(&at[k * 32 + ty * 4]);
            float4 w = *reinterpret_cast<const float4*>(&wl[k * D + tx * 4]);
            acc[0][0] += a.x * w.x; acc[0][1] += a.x * w.y; acc[0][2] += a.x * w.z; acc[0][3] += a.x * w.w;
            acc[1][0] += a.y * w.x; acc[1][1] += a.y * w.y; acc[1][2] += a.y * w.z; acc[1][3] += a.y * w.w;
            acc[2][0] += a.z * w.x; acc[2][1] += a.z * w.y; acc[2][2] += a.z * w.z; acc[2][3] += a.z * w.w;
            acc[3][0] += a.w * w.x; acc[3][1] += a.w * w.y; acc[3][2] += a.w * w.z; acc[3][3] += a.w * w.w;
        }

#pragma unroll
        for (int j = 0; j < 4; j++) {
            int gr = row0 + ty * 4 + j;
            if (gr < nrows) {
                float4 o;
                o.x = acc[j][0] + bv.x; o.y = acc[j][1] + bv.y;
                o.z = acc[j][2] + bv.z; o.w = acc[j][3] + bv.w;
                if (relu) {
                    o.x = fmaxf(o.x, 0.f); o.y = fmaxf(o.y, 0.f);
                    o.z = fmaxf(o.z, 0.f); o.w = fmaxf(o.w, 0.f);
                }
                if (head) {
                    cs0 += o.x; cs1 += o.y; cs2 += o.z; cs3 += o.w;
                    float pr = o.x * pwv.x + o.y * pwv.y + o.z * pwv.z + o.w * pwv.w;
#pragma unroll
                    for (int off = 16; off > 0; off >>= 1) pr += __shfl_xor(pr, off, 32);
                    if (tx == 0) pi_out[gr] = pr + pb0;
                } else {
                    if (dscale) {
                        float w = dscale[gr];
                        o.x *= w; o.y *= w; o.z *= w; o.w *= w;
                    }
                    *reinterpret_cast<float4*>(&out[(size_t)op * PANEL + (size_t)gr * 16 + oq * 4]) = o;
                }
            }
        }
    }

    if (head) {
        __syncthreads();
        float* csl = at;
        if (t < D) csl[t] = 0.f;
        __syncthreads();
        atomicAdd(&csl[tx * 4 + 0], cs0);
        atomicAdd(&csl[tx * 4 + 1], cs1);
        atomicAdd(&csl[tx * 4 + 2], cs2);
        atomicAdd(&csl[tx * 4 + 3], cs3);
        __syncthreads();
        if (t < D) atomicAdd(&colsum[t], csl[t]);
    }
}

// ---------------- value head ----------------

__global__ __launch_bounds__(128) void k_value(const float* __restrict__ colsum, const float* __restrict__ vw,
                                               const float* __restrict__ vb, float* __restrict__ out) {
    __shared__ float red[128];
    int t = threadIdx.x;
    red[t] = (colsum[t] * (1.0f / (float)N_NODES)) * vw[t];
    __syncthreads();
    for (int s = 64; s > 0; s >>= 1) {
        if (t < s) red[t] += red[t + s];
        __syncthreads();
    }
    if (t == 0) out[0] = red[0] + vb[0];
}

__global__ __launch_bounds__(64) void k_ws_too_small(float* __restrict__ out, int n) {
    int i = blockIdx.x * 64 + threadIdx.x;
    if (i < n) out[i] = -1e30f;
}

// ---------------- launch ----------------

extern "C" void kernel_launch(void* const* d_in, const int* in_sizes, int n_in,
                              void* d_out, int out_size, void* d_ws, size_t ws_size,
                              hipStream_t stream) {
    const float* features = (const float*)d_in[0];
    const int*   src      = (const int*)d_in[1];
    const int*   dst      = (const int*)d_in[2];
    const float* W1 = (const float*)d_in[3];
    const float* b1 = (const float*)d_in[4];
    const float* W2 = (const float*)d_in[5];
    const float* b2 = (const float*)d_in[6];
    const float* W3 = (const float*)d_in[7];
    const float* b3 = (const float*)d_in[8];
    const float* pw = (const float*)d_in[9];
    const float* pb = (const float*)d_in[10];
    const float* vw = (const float*)d_in[11];
    const float* vb = (const float*)d_in[12];
    float* out = (float*)d_out;

    char* ws = (char*)d_ws;
    size_t off = 0;
    auto alloc = [&](size_t bytes) -> char* {
        char* p = ws + off;
        off += (bytes + 255) & ~(size_t)255;
        return p;
    };
    float* dinv     = (float*)alloc((size_t)N_NODES * 4);
    int*   rowptr   = (int*)alloc((size_t)(N_NODES + 1) * 4);
    int*   blocksum = (int*)alloc(64 * 4);
    int*   blockoff = (int*)alloc(64 * 4);
    float* colsum   = (float*)alloc(D * 4);
    int*   csrc     = (int*)alloc((size_t)N_EDGES * 4);
    float* bufA     = (float*)alloc((size_t)N_NODES * D * 4);
    float* bufB     = (float*)alloc((size_t)N_NODES * D * 4);

    // CSR-build temporaries overlay bufB (dead once agg-1 writes bufB):
    // [degcnt: N][rowcnt: N][pos: NE] ints = 3.6 MB << 25.6 MB.
    int* degcnt = (int*)bufB;
    int* rowcnt = degcnt + N_NODES;
    int* pos    = rowcnt + N_NODES;

    if (off > ws_size) {
        k_ws_too_small<<<(out_size + 63) / 64, 64, 0, stream>>>(out, out_size);
        return;
    }

    hipMemsetAsync(degcnt, 0, (size_t)N_NODES * 4, stream);
    hipMemsetAsync(rowcnt, 0, (size_t)N_NODES * 4, stream);
    hipMemsetAsync(colsum, 0, (size_t)D * 4, stream);

    int eblocks = (N_EDGES + 255) / 256;
    k_count<<<eblocks, 256, 0, stream>>>(src, dst, degcnt, rowcnt, pos, N_EDGES);
    k_deginv<<<(N_NODES + 255) / 256, 256, 0, stream>>>(degcnt, dinv, N_NODES);

    int nblk = (N_NODES + 1023) / 1024;
    k_scan1<<<nblk, 1024, 0, stream>>>(rowcnt, rowptr, blocksum, N_NODES);
    k_scan2<<<1, 64, 0, stream>>>(blocksum, blockoff, rowptr + N_NODES, nblk);
    k_scan3<<<nblk, 1024, 0, stream>>>(rowptr, blockoff, N_NODES);
    k_fill<<<eblocks, 256, 0, stream>>>(src, dst, rowptr, pos, csrc, N_EDGES);

    // panelize features*dinv -> bufA (panels)
    k_panelize<<<(N_NODES * 32 + 255) / 256, 256, 0, stream>>>(features, dinv, bufA);

    int aggblocks = ((N_NODES + 63) / 64) * NSH;    // 782*8 = 6256
    // layer 1: agg(bufA)->bufB ; gemm in-place panels (+dinv scale for next layer)
    k_agg<<<aggblocks, 256, 0, stream>>>(bufA, rowptr, csrc, bufB);
    k_gemm<<<512, 256, 0, stream>>>(bufB, W1, b1, bufB, N_NODES, 1, dinv,
                                    nullptr, nullptr, nullptr, nullptr);
    // layer 2
    k_agg<<<aggblocks, 256, 0, stream>>>(bufB, rowptr, csrc, bufA);
    k_gemm<<<512, 256, 0, stream>>>(bufA, W2, b2, bufA, N_NODES, 1, dinv,
                                    nullptr, nullptr, nullptr, nullptr);
    // layer 3: head mode (PI -> out, colsum; h3 never stored)
    k_agg<<<aggblocks, 256, 0, stream>>>(bufA, rowptr, csrc, bufB);
    k_gemm<<<512, 256, 0, stream>>>(bufB, W3, b3, nullptr, N_NODES, 0, nullptr,
                                    pw, pb, out, colsum);

    k_value<<<1, 128, 0, stream>>>(colsum, vw, vb, out + N_NODES);
}